// Round 22
// baseline (127.156 us; speedup 1.0000x reference)
//
#include <hip/hip_runtime.h>
#include <hip/hip_bf16.h>

#define NF 768
#define NHEADS 12
#define NSEQ 2048
#define NX (8192 * 768)
#define NW (768 * 768)

// sqrt(0.125 * log2(e)) — folded softmax scale
#define QSC 0.42466090f

typedef __attribute__((__ext_vector_type__(8))) __bf16 bfrag;
typedef __attribute__((__ext_vector_type__(4))) float f32x4;
typedef __attribute__((__ext_vector_type__(16))) float f32x16;

// scalar f32 -> bf16 bits via HW cvt (compiler-visible, RNE)
static __device__ __forceinline__ unsigned short bfu(float f) {
    union { __hip_bfloat16 h; unsigned short u; } v;
    v.h = __float2bfloat16(f);
    return v.u;
}

// pack two f32 -> dword of 2 bf16 via HW cvt (lo in low 16 bits)
static __device__ __forceinline__ int packrn(float lo, float hi) {
    union { __hip_bfloat162 h; int i; } u;
    u.h.x = __float2bfloat16(lo);
    u.h.y = __float2bfloat16(hi);
    return u.i;
}

// exp2 via compiler-visible instruction (hazard recognizer can see it)
static __device__ __forceinline__ float exp2a(float x) {
#if __has_builtin(__builtin_amdgcn_exp2f)
    return __builtin_amdgcn_exp2f(x);
#else
    return exp2f(x);
#endif
}

// swap: a.hi32lanes <-> b.lo32lanes, via builtin (hazard-visible)
static __device__ __forceinline__ void plswap(int& a, int& b, int hi) {
#if __has_builtin(__builtin_amdgcn_permlane32_swap)
    auto r = __builtin_amdgcn_permlane32_swap((unsigned)a, (unsigned)b, false, false);
    a = (int)r[0]; b = (int)r[1];
#else
    int ta = __shfl_xor(b, 32), tb = __shfl_xor(a, 32);
    a = hi ? ta : a;
    b = hi ? b : tb;
#endif
}

// partner-half value of v (lane ^ 32)
static __device__ __forceinline__ float xhalf(float v, int hi) {
#if __has_builtin(__builtin_amdgcn_permlane32_swap)
    union { float f; unsigned u; } c; c.f = v;
    auto r = __builtin_amdgcn_permlane32_swap(c.u, c.u, false, false);
    union { unsigned u; float f; } d; d.u = hi ? r[0] : r[1];
    return d.f;
#else
    return __shfl_xor(v, 32);
#endif
}

// async global(16B/lane) -> LDS; linear dest = wave-uniform base + lane*16
static __device__ __forceinline__ void gload16(const unsigned short* g, unsigned short* l) {
#if __has_builtin(__builtin_amdgcn_global_load_lds)
    __builtin_amdgcn_global_load_lds(
        (const __attribute__((address_space(1))) void*)g,
        (__attribute__((address_space(3))) void*)l, 16, 0, 0);
#else
    *(uint4*)l = *(const uint4*)g;
#endif
}

// ---------------------------------------------------------------------------
// Preconvert: xb = bf16(x); W1b = bf16(QSC * Wqkv[:768,:]); W2b = bf16(Wproj)
// ---------------------------------------------------------------------------
__global__ __launch_bounds__(256) void preconv(const float* __restrict__ x,
                                               const float* __restrict__ W1,
                                               const float* __restrict__ W2,
                                               unsigned short* __restrict__ xb,
                                               unsigned short* __restrict__ W1b,
                                               unsigned short* __restrict__ W2b) {
    const size_t i = ((size_t)blockIdx.x * 256 + threadIdx.x) * 8;
    const float* src;
    unsigned short* dst;
    float scl = 1.0f;
    if (i < (size_t)NX) {
        src = x + i; dst = xb + i;
    } else if (i < (size_t)NX + NW) {
        const size_t j = i - NX;
        src = W1 + j; dst = W1b + j; scl = QSC;
    } else {
        const size_t j = i - NX - NW;
        src = W2 + j; dst = W2b + j;
    }
    float4 v0 = *(const float4*)(src);
    float4 v1 = *(const float4*)(src + 4);
    uint4 o;
    o.x = (unsigned)packrn(v0.x * scl, v0.y * scl);
    o.y = (unsigned)packrn(v0.z * scl, v0.w * scl);
    o.z = (unsigned)packrn(v1.x * scl, v1.y * scl);
    o.w = (unsigned)packrn(v1.z * scl, v1.w * scl);
    *(uint4*)dst = o;
}

// ---------------------------------------------------------------------------
// GEMM 1: Q' = xb @ W1b^T + QSC*bq   (M=8192, N=768, K=768), bf16 in, bf16 out
// R22: 64x64 tile -> grid 128*12 = 1536 blocks (6/CU), BK=64.
// Wave tile 32x32 (2x2 wave grid).  Staging via global_load_lds.
// ---------------------------------------------------------------------------
__global__ __launch_bounds__(256) void gemm_qkv(const unsigned short* __restrict__ A,
                                                const unsigned short* __restrict__ B,
                                                const float* __restrict__ bias,
                                                unsigned short* __restrict__ Qo) {
    __shared__ unsigned short As[2 * 64 * 32];
    __shared__ unsigned short Bs[2 * 64 * 32];
    const int t    = threadIdx.x;
    const int bm   = blockIdx.x / 12, bn = blockIdx.x % 12;
    const int m0   = bm * 64, n0 = bn * 64;
    const int lane = t & 63;
    const int wid  = t >> 6;
    const int wm   = (wid >> 1) * 32, wn = (wid & 1) * 32;

    const unsigned short* ga = A + (size_t)(m0 + (t >> 2)) * NF + (t & 3) * 8;
    const unsigned short* gb = B + (size_t)(n0 + (t >> 2)) * NF + (t & 3) * 8;

    f32x4 acc[2][2];
#pragma unroll
    for (int i = 0; i < 2; i++)
#pragma unroll
        for (int j = 0; j < 2; j++) acc[i][j] = (f32x4)0.0f;

    for (int k0 = 0; k0 < NF; k0 += 64) {
        gload16(ga + k0,      &As[t * 8]);
        gload16(ga + k0 + 32, &As[2048 + t * 8]);
        gload16(gb + k0,      &Bs[t * 8]);
        gload16(gb + k0 + 32, &Bs[2048 + t * 8]);
        __syncthreads();

#pragma unroll
        for (int kk = 0; kk < 2; kk++) {
            bfrag af[2], bfr[2];
#pragma unroll
            for (int i = 0; i < 2; i++)
                af[i]  = *(const bfrag*)&As[kk*2048 + (wm + i*16 + (lane & 15)) * 32 + (lane >> 4) * 8];
#pragma unroll
            for (int j = 0; j < 2; j++)
                bfr[j] = *(const bfrag*)&Bs[kk*2048 + (wn + j*16 + (lane & 15)) * 32 + (lane >> 4) * 8];
#pragma unroll
            for (int i = 0; i < 2; i++)
#pragma unroll
                for (int j = 0; j < 2; j++)
                    acc[i][j] = __builtin_amdgcn_mfma_f32_16x16x32_bf16(af[i], bfr[j], acc[i][j], 0, 0, 0);
        }
        __syncthreads();
    }

#pragma unroll
    for (int j = 0; j < 2; j++) {
        const int col = n0 + wn + j*16 + (lane & 15);
        const float bq = QSC * bias[col];
#pragma unroll
        for (int i = 0; i < 2; i++) {
            const int rbase = m0 + wm + i*16 + ((lane >> 4) << 2);
#pragma unroll
            for (int r = 0; r < 4; r++)
                Qo[(size_t)(rbase + r) * NF + col] = bfu(acc[i][j][r] + bq);
        }
    }
}

// ---------------------------------------------------------------------------
// GEMM 2: out = A @ W2b^T + bp   (M=8192, N=768, K=768), bf16 in, f32 out
// R22: 64x64 tile, 1536 blocks, BK=64.
// ---------------------------------------------------------------------------
__global__ __launch_bounds__(256) void gemm_proj(const unsigned short* __restrict__ A,
                                                 const unsigned short* __restrict__ B,
                                                 const float* __restrict__ bias,
                                                 float* __restrict__ out) {
    __shared__ unsigned short As[2 * 64 * 32];
    __shared__ unsigned short Bs[2 * 64 * 32];
    const int t    = threadIdx.x;
    const int bm   = blockIdx.x / 12, bn = blockIdx.x % 12;
    const int m0   = bm * 64, n0 = bn * 64;
    const int lane = t & 63;
    const int wid  = t >> 6;
    const int wm   = (wid >> 1) * 32, wn = (wid & 1) * 32;

    const unsigned short* ga = A + (size_t)(m0 + (t >> 2)) * NF + (t & 3) * 8;
    const unsigned short* gb = B + (size_t)(n0 + (t >> 2)) * NF + (t & 3) * 8;

    f32x4 acc[2][2];
#pragma unroll
    for (int i = 0; i < 2; i++)
#pragma unroll
        for (int j = 0; j < 2; j++) acc[i][j] = (f32x4)0.0f;

    for (int k0 = 0; k0 < NF; k0 += 64) {
        gload16(ga + k0,      &As[t * 8]);
        gload16(ga + k0 + 32, &As[2048 + t * 8]);
        gload16(gb + k0,      &Bs[t * 8]);
        gload16(gb + k0 + 32, &Bs[2048 + t * 8]);
        __syncthreads();

#pragma unroll
        for (int kk = 0; kk < 2; kk++) {
            bfrag af[2], bfr[2];
#pragma unroll
            for (int i = 0; i < 2; i++)
                af[i]  = *(const bfrag*)&As[kk*2048 + (wm + i*16 + (lane & 15)) * 32 + (lane >> 4) * 8];
#pragma unroll
            for (int j = 0; j < 2; j++)
                bfr[j] = *(const bfrag*)&Bs[kk*2048 + (wn + j*16 + (lane & 15)) * 32 + (lane >> 4) * 8];
#pragma unroll
            for (int i = 0; i < 2; i++)
#pragma unroll
                for (int j = 0; j < 2; j++)
                    acc[i][j] = __builtin_amdgcn_mfma_f32_16x16x32_bf16(af[i], bfr[j], acc[i][j], 0, 0, 0);
        }
        __syncthreads();
    }

#pragma unroll
    for (int j = 0; j < 2; j++) {
        const int col = n0 + wn + j*16 + (lane & 15);
        const float bvv = bias[col];
#pragma unroll
        for (int i = 0; i < 2; i++) {
            const int rbase = m0 + wm + i*16 + ((lane >> 4) << 2);
#pragma unroll
            for (int r = 0; r < 4; r++)
                out[(size_t)(rbase + r) * NF + col] = acc[i][j][r] + bvv;
        }
    }
}

// ---------------------------------------------------------------------------
// Flash-style causal attention, Q = K = V (pre-scaled by QSC in gemm_qkv).
// R21-verbatim (verified 78.7 us): 4-wave blocks, K-SPLIT (wave = (qsub, kh));
// independent online softmax per k-half; flash-combine merge via LDS;
// KVBLK=64, 16.9 KB LDS, pairing (uniform 33 iters).
// ---------------------------------------------------------------------------
__global__ __launch_bounds__(256, 1) void attn(const unsigned short* __restrict__ Q,
                                               unsigned short* __restrict__ O) {
    const int pair = blockIdx.x;         // 0..15
    const int bh   = blockIdx.y;         // 0..47
    const int b    = bh / NHEADS, h = bh % NHEADS;
    const unsigned short* base = Q + (size_t)b * NSEQ * NF + h * 64;
    unsigned short*       ob   = O + (size_t)b * NSEQ * NF + h * 64;

    const int t    = threadIdx.x;        // 0..255
    const int w    = t >> 6;             // wave 0..3
    const int qsub = w & 1;              // q-subtile (32 rows)
    const int kh   = w >> 1;             // k-half (32 kpos of each 64-k tile)
    const int l31  = t & 31;
    const int hi   = (t >> 5) & 1;
    const int sw   = l31 & 7;                          // Ks read swizzle key
    const int svw  = (l31 & 7) ^ ((l31 >> 2) & 7);     // Vt read swizzle key

    // 16 KB shared: K/V staging during k-loop; merge-O region afterward.
    __shared__ float smem[4096];
    unsigned short* Ks = (unsigned short*)smem;          // [64*64] bf16 = 8 KB
    unsigned short* Vt = (unsigned short*)smem + 4096;   // 8 KB
    float* mO = smem;                                    // [2][64*32] f32 = 16 KB
    __shared__ float ml[2][2][32];

    for (int half = 0; half < 2; half++) {
        const int qt  = half ? (31 - pair) : pair;
        const int wq0 = qt * 64 + qsub * 32;
        const int qg  = wq0 + l31;       // this lane's q row

        // Q B-fragments (n = q = lane&31; chunk c16 covers d = c16*16 + hi*8 ..)
        bfrag qf[4];
#pragma unroll
        for (int c16 = 0; c16 < 4; c16++)
            qf[c16] = *(const bfrag*)(base + (size_t)qg * NF + c16*16 + hi*8);

        f32x16 o[2];
#pragma unroll
        for (int fd = 0; fd < 2; fd++)
#pragma unroll
            for (int r = 0; r < 16; r++) o[fd][r] = 0.0f;
        float m_ = -3.0e38f, l_ = 0.0f;

        const int ktend = qt + 1;
        for (int kt = 0; kt < ktend; kt++) {
            const int k0 = kt * 64;

            // ---- stage: waves 0-1 do K (R15 map over 128 thr), 2-3 do V ----
            if (t < 128) {
                const int r = t >> 1, c = t & 1;
                const unsigned short* kg = base + (size_t)(k0 + r) * NF + c * 32;
#pragma unroll
                for (int i = 0; i < 4; i++) {
                    uint4 v = *(const uint4*)(kg + i * 8);
                    const int u = (4 * c + i) ^ (r & 7);
                    *(uint4*)&Ks[r * 64 + u * 8] = v;
                }
            } else {
                const int tt = t - 128;
                const int p = tt & 15, g2 = tt >> 4;   // d-group, k-group(8 rows)
                const unsigned short* vg = base + (size_t)(k0 + 8 * g2) * NF + 4 * p;
                uint2 ld[8];
#pragma unroll
                for (int i = 0; i < 8; i++) ld[i] = *(const uint2*)(vg + (size_t)i * NF);
#pragma unroll
                for (int j = 0; j < 4; j++) {
                    const int d = 4 * p + j;
                    union { unsigned short hh[8]; uint4 q; } wv;
#pragma unroll
                    for (int i = 0; i < 8; i++) wv.hh[i] = ((const unsigned short*)&ld[i])[j];
                    const int u = g2 ^ (d & 7) ^ ((d >> 2) & 7);
                    *(uint4*)&Vt[d * 64 + u * 8] = wv.q;
                }
            }
            __syncthreads();

            // wave live iff its k-half has any unmasked kpos for its rows
            if (k0 + 32 * kh <= wq0 + 31) {
                // ---- S' = K' Q'^T for this wave's kblk (exp2 domain) ----
                f32x16 s;
#pragma unroll
                for (int r = 0; r < 16; r++) s[r] = 0.0f;
                __builtin_amdgcn_s_setprio(1);
#pragma unroll
                for (int c16 = 0; c16 < 4; c16++) {
                    bfrag ka = *(const bfrag*)&Ks[(kh*32 + l31)*64 + (((2*c16 + hi) ^ sw) * 8)];
                    s = __builtin_amdgcn_mfma_f32_32x32x16_bf16(ka, qf[c16], s, 0, 0, 0);
                }
                __builtin_amdgcn_s_setprio(0);

                // ---- causal mask if this kblk overlaps the diagonal ----
                if (k0 + 32*kh + 31 > wq0) {
#pragma unroll
                    for (int r = 0; r < 16; r++) {
                        const int kp = k0 + 32*kh + (r & 3) + 8*(r >> 2) + 4*hi;
                        if (kp > qg) s[r] = -1.0e30f;
                    }
                }

                // ---- online softmax (exp2 domain, THR=8 defer-max) ----
                float mx = -3.0e38f;
#pragma unroll
                for (int r = 0; r < 16; r++) mx = fmaxf(mx, s[r]);
                mx = fmaxf(mx, xhalf(mx, hi));

                const bool nogrow = __all(mx <= m_ + 8.0f);
                const float mn = nogrow ? m_ : fmaxf(m_, mx);
                float rs = 0.0f;
#pragma unroll
                for (int r = 0; r < 16; r++) {
                    const float p = exp2a(s[r] - mn);
                    s[r] = p;
                    rs += p;
                }
                rs += xhalf(rs, hi);
                if (nogrow) {
                    l_ += rs;
                } else {
                    const float sc = exp2a(m_ - mn);
                    l_ = l_ * sc + rs;
                    m_ = mn;
#pragma unroll
                    for (int fd = 0; fd < 2; fd++)
#pragma unroll
                        for (int r = 0; r < 16; r++) o[fd][r] *= sc;
                }

                // ---- P -> bf16 B-frags ; O^T += V^T P for this kblk ----
                int wv_[4][2];
#pragma unroll
                for (int f = 0; f < 4; f++)
#pragma unroll
                    for (int rr = 0; rr < 2; rr++)
                        wv_[f][rr] = packrn(s[4*f + 2*rr], s[4*f + 2*rr + 1]);
#pragma unroll
                for (int c = 0; c < 2; c++) {
                    int x0 = wv_[2*c][0], y0 = wv_[2*c+1][0];
                    plswap(x0, y0, hi);
                    int x1 = wv_[2*c][1], y1 = wv_[2*c+1][1];
                    plswap(x1, y1, hi);
                    union { int d[4]; bfrag f; } pf;
                    pf.d[0] = x0; pf.d[1] = x1; pf.d[2] = y0; pf.d[3] = y1;
                    const int ck = kh*2 + c;
                    __builtin_amdgcn_s_setprio(1);
#pragma unroll
                    for (int fd = 0; fd < 2; fd++) {
                        bfrag va = *(const bfrag*)&Vt[(fd*32 + l31)*64 + (((2*ck + hi) ^ svw) * 8)];
                        o[fd] = __builtin_amdgcn_mfma_f32_32x32x16_bf16(va, pf.f, o[fd], 0, 0, 0);
                    }
                    __builtin_amdgcn_s_setprio(0);
                }
            }
            __syncthreads();
        }

        // ---- merge partials across k-halves (flash combine) ----
        // kh=1 waves publish O (transposed: addr = d*32 + q, conflict-free), m, l
        if (kh == 1) {
#pragma unroll
            for (int fd = 0; fd < 2; fd++)
#pragma unroll
                for (int r = 0; r < 16; r++) {
                    const int d = 32*fd + 8*(r >> 2) + 4*hi + (r & 3);
                    mO[qsub * 2048 + d * 32 + l31] = o[fd][r];
                }
            if (hi == 0) { ml[qsub][0][l31] = m_; ml[qsub][1][l31] = l_; }
        }
        __syncthreads();

        if (kh == 0) {
            const float mB = ml[qsub][0][l31];
            const float lB = ml[qsub][1][l31];
            const float mm = fmaxf(m_, mB);
            const float aa = exp2a(m_ - mm);
            const float bb = exp2a(mB - mm);
            const float ll = l_ * aa + lB * bb;
            const float inv = 1.0f / (ll * QSC);
#pragma unroll
            for (int fd = 0; fd < 2; fd++) {
                float ov[16];
#pragma unroll
                for (int r = 0; r < 16; r++) {
                    const int d = 32*fd + 8*(r >> 2) + 4*hi + (r & 3);
                    ov[r] = (o[fd][r] * aa + mO[qsub * 2048 + d * 32 + l31] * bb) * inv;
                }
#pragma unroll
                for (int f = 0; f < 4; f++) {
                    const int d0 = fd*32 + 8*f + 4*hi;
                    uint2 pr;
                    pr.x = (unsigned)packrn(ov[4*f+0], ov[4*f+1]);
                    pr.y = (unsigned)packrn(ov[4*f+2], ov[4*f+3]);
                    *(uint2*)(ob + (size_t)qg * NF + d0) = pr;
                }
            }
        }
        __syncthreads();
    }
}

extern "C" void kernel_launch(void* const* d_in, const int* in_sizes, int n_in,
                              void* d_out, int out_size, void* d_ws, size_t ws_size,
                              hipStream_t stream) {
    const float* x    = (const float*)d_in[0];
    const float* Wqkv = (const float*)d_in[1];
    const float* bqkv = (const float*)d_in[2];
    const float* Wp   = (const float*)d_in[3];
    const float* bp   = (const float*)d_in[4];
    float* out        = (float*)d_out;

    unsigned short* Qws = (unsigned short*)d_ws;        // 12.6 MB
    unsigned short* Aws = Qws + (size_t)NX;             // 12.6 MB
    unsigned short* xb  = Aws + (size_t)NX;             // 12.6 MB
    unsigned short* W1b = xb + (size_t)NX;              // 1.18 MB
    unsigned short* W2b = W1b + (size_t)NW;             // 1.18 MB

    preconv<<<3648, 256, 0, stream>>>(x, Wqkv, Wp, xb, W1b, W2b);
    gemm_qkv<<<1536, 256, 0, stream>>>(xb, W1b, bqkv, Qws);
    attn<<<dim3(16, 48), 256, 0, stream>>>(Qws, Aws);
    gemm_proj<<<1536, 256, 0, stream>>>(Aws, W2b, bp, out);
}

// Round 23
// 120.419 us; speedup vs baseline: 1.0559x; 1.0559x over previous
//
#include <hip/hip_runtime.h>
#include <hip/hip_bf16.h>

#define NF 768
#define NHEADS 12
#define NSEQ 2048
#define NX (8192 * 768)
#define NW (768 * 768)

// sqrt(0.125 * log2(e)) — folded softmax scale
#define QSC 0.42466090f

typedef __attribute__((__ext_vector_type__(8))) __bf16 bfrag;
typedef __attribute__((__ext_vector_type__(4))) float f32x4;
typedef __attribute__((__ext_vector_type__(16))) float f32x16;

// scalar f32 -> bf16 bits via HW cvt (compiler-visible, RNE)
static __device__ __forceinline__ unsigned short bfu(float f) {
    union { __hip_bfloat16 h; unsigned short u; } v;
    v.h = __float2bfloat16(f);
    return v.u;
}

// pack two f32 -> dword of 2 bf16 via HW cvt (lo in low 16 bits)
static __device__ __forceinline__ int packrn(float lo, float hi) {
    union { __hip_bfloat162 h; int i; } u;
    u.h.x = __float2bfloat16(lo);
    u.h.y = __float2bfloat16(hi);
    return u.i;
}

// exp2 via compiler-visible instruction (hazard recognizer can see it)
static __device__ __forceinline__ float exp2a(float x) {
#if __has_builtin(__builtin_amdgcn_exp2f)
    return __builtin_amdgcn_exp2f(x);
#else
    return exp2f(x);
#endif
}

// swap: a.hi32lanes <-> b.lo32lanes, via builtin (hazard-visible)
static __device__ __forceinline__ void plswap(int& a, int& b, int hi) {
#if __has_builtin(__builtin_amdgcn_permlane32_swap)
    auto r = __builtin_amdgcn_permlane32_swap((unsigned)a, (unsigned)b, false, false);
    a = (int)r[0]; b = (int)r[1];
#else
    int ta = __shfl_xor(b, 32), tb = __shfl_xor(a, 32);
    a = hi ? ta : a;
    b = hi ? b : tb;
#endif
}

// partner-half value of v (lane ^ 32)
static __device__ __forceinline__ float xhalf(float v, int hi) {
#if __has_builtin(__builtin_amdgcn_permlane32_swap)
    union { float f; unsigned u; } c; c.f = v;
    auto r = __builtin_amdgcn_permlane32_swap(c.u, c.u, false, false);
    union { unsigned u; float f; } d; d.u = hi ? r[0] : r[1];
    return d.f;
#else
    return __shfl_xor(v, 32);
#endif
}

// async global(16B/lane) -> LDS; linear dest = wave-uniform base + lane*16
static __device__ __forceinline__ void gload16(const unsigned short* g, unsigned short* l) {
#if __has_builtin(__builtin_amdgcn_global_load_lds)
    __builtin_amdgcn_global_load_lds(
        (const __attribute__((address_space(1))) void*)g,
        (__attribute__((address_space(3))) void*)l, 16, 0, 0);
#else
    *(uint4*)l = *(const uint4*)g;
#endif
}

// ---------------------------------------------------------------------------
// Preconvert: xb = bf16(x); W1b = bf16(QSC * Wqkv[:768,:]); W2b = bf16(Wproj)
// ---------------------------------------------------------------------------
__global__ __launch_bounds__(256) void preconv(const float* __restrict__ x,
                                               const float* __restrict__ W1,
                                               const float* __restrict__ W2,
                                               unsigned short* __restrict__ xb,
                                               unsigned short* __restrict__ W1b,
                                               unsigned short* __restrict__ W2b) {
    const size_t i = ((size_t)blockIdx.x * 256 + threadIdx.x) * 8;
    const float* src;
    unsigned short* dst;
    float scl = 1.0f;
    if (i < (size_t)NX) {
        src = x + i; dst = xb + i;
    } else if (i < (size_t)NX + NW) {
        const size_t j = i - NX;
        src = W1 + j; dst = W1b + j; scl = QSC;
    } else {
        const size_t j = i - NX - NW;
        src = W2 + j; dst = W2b + j;
    }
    float4 v0 = *(const float4*)(src);
    float4 v1 = *(const float4*)(src + 4);
    uint4 o;
    o.x = (unsigned)packrn(v0.x * scl, v0.y * scl);
    o.y = (unsigned)packrn(v0.z * scl, v0.w * scl);
    o.z = (unsigned)packrn(v1.x * scl, v1.y * scl);
    o.w = (unsigned)packrn(v1.z * scl, v1.w * scl);
    *(uint4*)dst = o;
}

// ---------------------------------------------------------------------------
// GEMM 1: Q' = xb @ W1b^T + QSC*bq   (M=8192, N=768, K=768), bf16 in, bf16 out
// 64x128 tile, 768 blocks, BK=64 (two [.][32] halves -> 12 barrier epochs).
// ---------------------------------------------------------------------------
__global__ __launch_bounds__(256) void gemm_qkv(const unsigned short* __restrict__ A,
                                                const unsigned short* __restrict__ B,
                                                const float* __restrict__ bias,
                                                unsigned short* __restrict__ Qo) {
    __shared__ unsigned short As[2 * 64 * 32];
    __shared__ unsigned short Bs[2 * 128 * 32];
    const int t    = threadIdx.x;
    const int bm   = blockIdx.x / 6, bn = blockIdx.x % 6;
    const int m0   = bm * 64, n0 = bn * 128;
    const int lane = t & 63;
    const int wid  = t >> 6;
    const int wm   = (wid >> 1) * 32, wn = (wid & 1) * 64;

    const unsigned short* ga  = A + (size_t)(m0 + (t >> 2)) * NF + (t & 3) * 8;
    const unsigned short* gb  = B + (size_t)(n0 + (t >> 2)) * NF + (t & 3) * 8;
    const unsigned short* gb2 = gb + (size_t)64 * NF;

    f32x4 acc[2][4];
#pragma unroll
    for (int i = 0; i < 2; i++)
#pragma unroll
        for (int j = 0; j < 4; j++) acc[i][j] = (f32x4)0.0f;

    for (int k0 = 0; k0 < NF; k0 += 64) {
        gload16(ga + k0,       &As[t * 8]);
        gload16(ga + k0 + 32,  &As[2048 + t * 8]);
        gload16(gb + k0,       &Bs[t * 8]);
        gload16(gb + k0 + 32,  &Bs[4096 + t * 8]);
        gload16(gb2 + k0,      &Bs[2048 + t * 8]);
        gload16(gb2 + k0 + 32, &Bs[4096 + 2048 + t * 8]);
        __syncthreads();

#pragma unroll
        for (int kk = 0; kk < 2; kk++) {
            bfrag af[2], bfr[4];
#pragma unroll
            for (int i = 0; i < 2; i++)
                af[i]  = *(const bfrag*)&As[kk*2048 + (wm + i*16 + (lane & 15)) * 32 + (lane >> 4) * 8];
#pragma unroll
            for (int j = 0; j < 4; j++)
                bfr[j] = *(const bfrag*)&Bs[kk*4096 + (wn + j*16 + (lane & 15)) * 32 + (lane >> 4) * 8];
#pragma unroll
            for (int i = 0; i < 2; i++)
#pragma unroll
                for (int j = 0; j < 4; j++)
                    acc[i][j] = __builtin_amdgcn_mfma_f32_16x16x32_bf16(af[i], bfr[j], acc[i][j], 0, 0, 0);
        }
        __syncthreads();
    }

#pragma unroll
    for (int j = 0; j < 4; j++) {
        const int col = n0 + wn + j*16 + (lane & 15);
        const float bq = QSC * bias[col];
#pragma unroll
        for (int i = 0; i < 2; i++) {
            const int rbase = m0 + wm + i*16 + ((lane >> 4) << 2);
#pragma unroll
            for (int r = 0; r < 4; r++)
                Qo[(size_t)(rbase + r) * NF + col] = bfu(acc[i][j][r] + bq);
        }
    }
}

// ---------------------------------------------------------------------------
// GEMM 2: out = A @ W2b^T + bp   (M=8192, N=768, K=768), bf16 in, f32 out
// BK=64 like gemm_qkv.
// ---------------------------------------------------------------------------
__global__ __launch_bounds__(256) void gemm_proj(const unsigned short* __restrict__ A,
                                                 const unsigned short* __restrict__ B,
                                                 const float* __restrict__ bias,
                                                 float* __restrict__ out) {
    __shared__ unsigned short As[2 * 64 * 32];
    __shared__ unsigned short Bs[2 * 128 * 32];
    const int t    = threadIdx.x;
    const int bm   = blockIdx.x / 6, bn = blockIdx.x % 6;
    const int m0   = bm * 64, n0 = bn * 128;
    const int lane = t & 63;
    const int wid  = t >> 6;
    const int wm   = (wid >> 1) * 32, wn = (wid & 1) * 64;

    const unsigned short* ga  = A + (size_t)(m0 + (t >> 2)) * NF + (t & 3) * 8;
    const unsigned short* gb  = B + (size_t)(n0 + (t >> 2)) * NF + (t & 3) * 8;
    const unsigned short* gb2 = gb + (size_t)64 * NF;

    f32x4 acc[2][4];
#pragma unroll
    for (int i = 0; i < 2; i++)
#pragma unroll
        for (int j = 0; j < 4; j++) acc[i][j] = (f32x4)0.0f;

    for (int k0 = 0; k0 < NF; k0 += 64) {
        gload16(ga + k0,       &As[t * 8]);
        gload16(ga + k0 + 32,  &As[2048 + t * 8]);
        gload16(gb + k0,       &Bs[t * 8]);
        gload16(gb + k0 + 32,  &Bs[4096 + t * 8]);
        gload16(gb2 + k0,      &Bs[2048 + t * 8]);
        gload16(gb2 + k0 + 32, &Bs[4096 + 2048 + t * 8]);
        __syncthreads();

#pragma unroll
        for (int kk = 0; kk < 2; kk++) {
            bfrag af[2], bfr[4];
#pragma unroll
            for (int i = 0; i < 2; i++)
                af[i]  = *(const bfrag*)&As[kk*2048 + (wm + i*16 + (lane & 15)) * 32 + (lane >> 4) * 8];
#pragma unroll
            for (int j = 0; j < 4; j++)
                bfr[j] = *(const bfrag*)&Bs[kk*4096 + (wn + j*16 + (lane & 15)) * 32 + (lane >> 4) * 8];
#pragma unroll
            for (int i = 0; i < 2; i++)
#pragma unroll
                for (int j = 0; j < 4; j++)
                    acc[i][j] = __builtin_amdgcn_mfma_f32_16x16x32_bf16(af[i], bfr[j], acc[i][j], 0, 0, 0);
        }
        __syncthreads();
    }

#pragma unroll
    for (int j = 0; j < 4; j++) {
        const int col = n0 + wn + j*16 + (lane & 15);
        const float bvv = bias[col];
#pragma unroll
        for (int i = 0; i < 2; i++) {
            const int rbase = m0 + wm + i*16 + ((lane >> 4) << 2);
#pragma unroll
            for (int r = 0; r < 4; r++)
                out[(size_t)(rbase + r) * NF + col] = acc[i][j][r] + bvv;
        }
    }
}

// ---------------------------------------------------------------------------
// Flash-style causal attention, Q = K = V (pre-scaled by QSC in gemm_qkv).
// R21-verbatim (verified 78.7 us): 4-wave blocks, K-SPLIT (wave = (qsub, kh));
// independent online softmax per k-half; flash-combine merge via LDS;
// KVBLK=64, 16.9 KB LDS, pairing (uniform 33 iters).
// ---------------------------------------------------------------------------
__global__ __launch_bounds__(256, 1) void attn(const unsigned short* __restrict__ Q,
                                               unsigned short* __restrict__ O) {
    const int pair = blockIdx.x;         // 0..15
    const int bh   = blockIdx.y;         // 0..47
    const int b    = bh / NHEADS, h = bh % NHEADS;
    const unsigned short* base = Q + (size_t)b * NSEQ * NF + h * 64;
    unsigned short*       ob   = O + (size_t)b * NSEQ * NF + h * 64;

    const int t    = threadIdx.x;        // 0..255
    const int w    = t >> 6;             // wave 0..3
    const int qsub = w & 1;              // q-subtile (32 rows)
    const int kh   = w >> 1;             // k-half (32 kpos of each 64-k tile)
    const int l31  = t & 31;
    const int hi   = (t >> 5) & 1;
    const int sw   = l31 & 7;                          // Ks read swizzle key
    const int svw  = (l31 & 7) ^ ((l31 >> 2) & 7);     // Vt read swizzle key

    // 16 KB shared: K/V staging during k-loop; merge-O region afterward.
    __shared__ float smem[4096];
    unsigned short* Ks = (unsigned short*)smem;          // [64*64] bf16 = 8 KB
    unsigned short* Vt = (unsigned short*)smem + 4096;   // 8 KB
    float* mO = smem;                                    // [2][64*32] f32 = 16 KB
    __shared__ float ml[2][2][32];

    for (int half = 0; half < 2; half++) {
        const int qt  = half ? (31 - pair) : pair;
        const int wq0 = qt * 64 + qsub * 32;
        const int qg  = wq0 + l31;       // this lane's q row

        // Q B-fragments (n = q = lane&31; chunk c16 covers d = c16*16 + hi*8 ..)
        bfrag qf[4];
#pragma unroll
        for (int c16 = 0; c16 < 4; c16++)
            qf[c16] = *(const bfrag*)(base + (size_t)qg * NF + c16*16 + hi*8);

        f32x16 o[2];
#pragma unroll
        for (int fd = 0; fd < 2; fd++)
#pragma unroll
            for (int r = 0; r < 16; r++) o[fd][r] = 0.0f;
        float m_ = -3.0e38f, l_ = 0.0f;

        const int ktend = qt + 1;
        for (int kt = 0; kt < ktend; kt++) {
            const int k0 = kt * 64;

            // ---- stage: waves 0-1 do K (R15 map over 128 thr), 2-3 do V ----
            if (t < 128) {
                const int r = t >> 1, c = t & 1;
                const unsigned short* kg = base + (size_t)(k0 + r) * NF + c * 32;
#pragma unroll
                for (int i = 0; i < 4; i++) {
                    uint4 v = *(const uint4*)(kg + i * 8);
                    const int u = (4 * c + i) ^ (r & 7);
                    *(uint4*)&Ks[r * 64 + u * 8] = v;
                }
            } else {
                const int tt = t - 128;
                const int p = tt & 15, g2 = tt >> 4;   // d-group, k-group(8 rows)
                const unsigned short* vg = base + (size_t)(k0 + 8 * g2) * NF + 4 * p;
                uint2 ld[8];
#pragma unroll
                for (int i = 0; i < 8; i++) ld[i] = *(const uint2*)(vg + (size_t)i * NF);
#pragma unroll
                for (int j = 0; j < 4; j++) {
                    const int d = 4 * p + j;
                    union { unsigned short hh[8]; uint4 q; } wv;
#pragma unroll
                    for (int i = 0; i < 8; i++) wv.hh[i] = ((const unsigned short*)&ld[i])[j];
                    const int u = g2 ^ (d & 7) ^ ((d >> 2) & 7);
                    *(uint4*)&Vt[d * 64 + u * 8] = wv.q;
                }
            }
            __syncthreads();

            // wave live iff its k-half has any unmasked kpos for its rows
            if (k0 + 32 * kh <= wq0 + 31) {
                // ---- S' = K' Q'^T for this wave's kblk (exp2 domain) ----
                f32x16 s;
#pragma unroll
                for (int r = 0; r < 16; r++) s[r] = 0.0f;
                __builtin_amdgcn_s_setprio(1);
#pragma unroll
                for (int c16 = 0; c16 < 4; c16++) {
                    bfrag ka = *(const bfrag*)&Ks[(kh*32 + l31)*64 + (((2*c16 + hi) ^ sw) * 8)];
                    s = __builtin_amdgcn_mfma_f32_32x32x16_bf16(ka, qf[c16], s, 0, 0, 0);
                }
                __builtin_amdgcn_s_setprio(0);

                // ---- causal mask if this kblk overlaps the diagonal ----
                if (k0 + 32*kh + 31 > wq0) {
#pragma unroll
                    for (int r = 0; r < 16; r++) {
                        const int kp = k0 + 32*kh + (r & 3) + 8*(r >> 2) + 4*hi;
                        if (kp > qg) s[r] = -1.0e30f;
                    }
                }

                // ---- online softmax (exp2 domain, THR=8 defer-max) ----
                float mx = -3.0e38f;
#pragma unroll
                for (int r = 0; r < 16; r++) mx = fmaxf(mx, s[r]);
                mx = fmaxf(mx, xhalf(mx, hi));

                const bool nogrow = __all(mx <= m_ + 8.0f);
                const float mn = nogrow ? m_ : fmaxf(m_, mx);
                float rs = 0.0f;
#pragma unroll
                for (int r = 0; r < 16; r++) {
                    const float p = exp2a(s[r] - mn);
                    s[r] = p;
                    rs += p;
                }
                rs += xhalf(rs, hi);
                if (nogrow) {
                    l_ += rs;
                } else {
                    const float sc = exp2a(m_ - mn);
                    l_ = l_ * sc + rs;
                    m_ = mn;
#pragma unroll
                    for (int fd = 0; fd < 2; fd++)
#pragma unroll
                        for (int r = 0; r < 16; r++) o[fd][r] *= sc;
                }

                // ---- P -> bf16 B-frags ; O^T += V^T P for this kblk ----
                int wv_[4][2];
#pragma unroll
                for (int f = 0; f < 4; f++)
#pragma unroll
                    for (int rr = 0; rr < 2; rr++)
                        wv_[f][rr] = packrn(s[4*f + 2*rr], s[4*f + 2*rr + 1]);
#pragma unroll
                for (int c = 0; c < 2; c++) {
                    int x0 = wv_[2*c][0], y0 = wv_[2*c+1][0];
                    plswap(x0, y0, hi);
                    int x1 = wv_[2*c][1], y1 = wv_[2*c+1][1];
                    plswap(x1, y1, hi);
                    union { int d[4]; bfrag f; } pf;
                    pf.d[0] = x0; pf.d[1] = x1; pf.d[2] = y0; pf.d[3] = y1;
                    const int ck = kh*2 + c;
                    __builtin_amdgcn_s_setprio(1);
#pragma unroll
                    for (int fd = 0; fd < 2; fd++) {
                        bfrag va = *(const bfrag*)&Vt[(fd*32 + l31)*64 + (((2*ck + hi) ^ svw) * 8)];
                        o[fd] = __builtin_amdgcn_mfma_f32_32x32x16_bf16(va, pf.f, o[fd], 0, 0, 0);
                    }
                    __builtin_amdgcn_s_setprio(0);
                }
            }
            __syncthreads();
        }

        // ---- merge partials across k-halves (flash combine) ----
        // kh=1 waves publish O (transposed: addr = d*32 + q, conflict-free), m, l
        if (kh == 1) {
#pragma unroll
            for (int fd = 0; fd < 2; fd++)
#pragma unroll
                for (int r = 0; r < 16; r++) {
                    const int d = 32*fd + 8*(r >> 2) + 4*hi + (r & 3);
                    mO[qsub * 2048 + d * 32 + l31] = o[fd][r];
                }
            if (hi == 0) { ml[qsub][0][l31] = m_; ml[qsub][1][l31] = l_; }
        }
        __syncthreads();

        if (kh == 0) {
            const float mB = ml[qsub][0][l31];
            const float lB = ml[qsub][1][l31];
            const float mm = fmaxf(m_, mB);
            const float aa = exp2a(m_ - mm);
            const float bb = exp2a(mB - mm);
            const float ll = l_ * aa + lB * bb;
            const float inv = 1.0f / (ll * QSC);
#pragma unroll
            for (int fd = 0; fd < 2; fd++) {
                float ov[16];
#pragma unroll
                for (int r = 0; r < 16; r++) {
                    const int d = 32*fd + 8*(r >> 2) + 4*hi + (r & 3);
                    ov[r] = (o[fd][r] * aa + mO[qsub * 2048 + d * 32 + l31] * bb) * inv;
                }
#pragma unroll
                for (int f = 0; f < 4; f++) {
                    const int d0 = fd*32 + 8*f + 4*hi;
                    uint2 pr;
                    pr.x = (unsigned)packrn(ov[4*f+0], ov[4*f+1]);
                    pr.y = (unsigned)packrn(ov[4*f+2], ov[4*f+3]);
                    *(uint2*)(ob + (size_t)qg * NF + d0) = pr;
                }
            }
        }
        __syncthreads();
    }
}

extern "C" void kernel_launch(void* const* d_in, const int* in_sizes, int n_in,
                              void* d_out, int out_size, void* d_ws, size_t ws_size,
                              hipStream_t stream) {
    const float* x    = (const float*)d_in[0];
    const float* Wqkv = (const float*)d_in[1];
    const float* bqkv = (const float*)d_in[2];
    const float* Wp   = (const float*)d_in[3];
    const float* bp   = (const float*)d_in[4];
    float* out        = (float*)d_out;

    unsigned short* Qws = (unsigned short*)d_ws;        // 12.6 MB
    unsigned short* Aws = Qws + (size_t)NX;             // 12.6 MB
    unsigned short* xb  = Aws + (size_t)NX;             // 12.6 MB
    unsigned short* W1b = xb + (size_t)NX;              // 1.18 MB
    unsigned short* W2b = W1b + (size_t)NW;             // 1.18 MB

    preconv<<<3648, 256, 0, stream>>>(x, Wqkv, Wp, xb, W1b, W2b);
    gemm_qkv<<<768, 256, 0, stream>>>(xb, W1b, bqkv, Qws);
    attn<<<dim3(16, 48), 256, 0, stream>>>(Qws, Aws);
    gemm_proj<<<768, 256, 0, stream>>>(Aws, W2b, bp, out);
}